// Round 1
// baseline (176.825 us; speedup 1.0000x reference)
//
#include <hip/hip_runtime.h>
#include <math.h>

// Problem constants (from reference)
#define BB 4
#define HH 704
#define WW 704
#define MM 32
#define PP 128
#define NNEG 129
#define RR 1
#define GAIN 2.0f
#define HW (HH * WW)

// Only losses[-1] (batch b = B-1 = 3) is returned by the reference.
// Total work: 2*(P+NN) log-softmax terms + M*R*2*7 smooth-L1 terms.
// One block of 256 threads does everything; block-reduce -> out[0].

__global__ __launch_bounds__(256) void loss_total_kernel(
    const float* __restrict__ rb,      // (B, M, 7)
    const float* __restrict__ pc,      // (B, 4, H, W)
    const float* __restrict__ pr,      // (B, 14, H, W)
    const float* __restrict__ anchor,  // (2, 7, H, W)
    const int* __restrict__ pidx,      // (B, P, 2)
    const int* __restrict__ nidx,      // (B, NN, 2)
    const int* __restrict__ ridx,      // (B, M, R, 2)
    float* __restrict__ out)           // scalar
{
    const int tid = threadIdx.x;
    const int b = BB - 1;

    const float* rb_b   = rb   + (size_t)b * MM * 7;
    const float* pc_b   = pc   + (size_t)b * 4 * HW;
    const float* pr_b   = pr   + (size_t)b * 14 * HW;
    const int*   pidx_b = pidx + (size_t)b * PP * 2;
    const int*   nidx_b = nidx + (size_t)b * NNEG * 2;
    const int*   ridx_b = ridx + (size_t)b * MM * RR * 2;

    float acc = 0.0f;

    // ---- classification: positive samples, label=1 (channel a0+1) ----
    // 2*P = 256 terms: i -> (a0idx = i/P in {0,1} -> channel pair {0,1} or {2,3}, p = i%P)
    for (int i = tid; i < 2 * PP; i += 256) {
        int a0 = (i / PP) * 2;
        int p  = i % PP;
        int y = pidx_b[p * 2 + 0];
        int x = pidx_b[p * 2 + 1];
        float l0 = pc_b[(size_t)a0       * HW + (size_t)y * WW + x];
        float l1 = pc_b[(size_t)(a0 + 1) * HW + (size_t)y * WW + x];
        float mx  = fmaxf(l0, l1);
        float lse = mx + logf(expf(l0 - mx) + expf(l1 - mx));
        acc += (lse - l1) * (1.0f / PP);   // -log_softmax[:,1] mean
    }

    // ---- classification: negative samples, label=0 (channel a0) ----
    for (int i = tid; i < 2 * NNEG; i += 256) {
        int a0 = (i / NNEG) * 2;
        int n  = i % NNEG;
        int y = nidx_b[n * 2 + 0];
        int x = nidx_b[n * 2 + 1];
        float l0 = pc_b[(size_t)a0       * HW + (size_t)y * WW + x];
        float l1 = pc_b[(size_t)(a0 + 1) * HW + (size_t)y * WW + x];
        float mx  = fmaxf(l0, l1);
        float lse = mx + logf(expf(l0 - mx) + expf(l1 - mx));
        acc += (lse - l0) * (1.0f / NNEG); // -log_softmax[:,0] mean
    }

    // ---- regression: M*R*2 (m, r, a) items, 7 components each ----
    for (int i = tid; i < MM * RR * 2; i += 256) {
        int a  = i & 1;
        int mr = i >> 1;
        int m  = mr / RR;
        int r  = mr % RR;
        int y = ridx_b[(m * RR + r) * 2 + 0];
        int x = ridx_b[(m * RR + r) * 2 + 1];
        size_t pix = (size_t)y * WW + x;

        float ab[7], pb[7], rf[7];
        #pragma unroll
        for (int k = 0; k < 7; ++k) {
            ab[k] = anchor[(size_t)(a * 7 + k) * HW + pix];
            pb[k] = pr_b  [(size_t)(a * 7 + k) * HW + pix];
            rf[k] = rb_b[m * 7 + k];
        }

        float diag = sqrtf(ab[3] * ab[3] + ab[4] * ab[4]);
        float off[7];
        off[0] = (rf[0] - ab[0]) / diag;
        off[1] = (rf[1] - ab[1]) / diag;
        off[2] = (rf[2] - ab[2]) / ab[5];
        off[3] = logf(rf[3] / ab[3]);
        off[4] = logf(rf[4] / ab[4]);
        off[5] = logf(rf[5] / ab[5]);
        float dth = rf[6] - ab[6];
        off[6] = atan2f(sinf(dth), cosf(dth));

        float s = 0.0f;
        #pragma unroll
        for (int k = 0; k < 7; ++k) {
            float d = pb[k] - off[k];
            float ad = fabsf(d);
            s += (ad < 1.0f) ? 0.5f * d * d : (ad - 0.5f);
        }
        // mean over (R,2,7) = divide by R*2*7, summed over m; then * GAIN
        acc += s * (GAIN / (float)(RR * 2 * 7));
    }

    // ---- block reduction: 4 waves of 64 ----
    #pragma unroll
    for (int off = 32; off > 0; off >>= 1)
        acc += __shfl_down(acc, off, 64);

    __shared__ float wsum[4];
    int wave = tid >> 6;
    int lane = tid & 63;
    if (lane == 0) wsum[wave] = acc;
    __syncthreads();
    if (tid == 0)
        out[0] = wsum[0] + wsum[1] + wsum[2] + wsum[3];
}

extern "C" void kernel_launch(void* const* d_in, const int* in_sizes, int n_in,
                              void* d_out, int out_size, void* d_ws, size_t ws_size,
                              hipStream_t stream) {
    const float* rb     = (const float*)d_in[0];
    const float* pc     = (const float*)d_in[1];
    const float* pr     = (const float*)d_in[2];
    const float* anchor = (const float*)d_in[3];
    const int*   pidx   = (const int*)d_in[4];
    const int*   nidx   = (const int*)d_in[5];
    const int*   ridx   = (const int*)d_in[6];
    float* out = (float*)d_out;

    loss_total_kernel<<<1, 256, 0, stream>>>(rb, pc, pr, anchor, pidx, nidx, ridx, out);
}

// Round 2
// 173.698 us; speedup vs baseline: 1.0180x; 1.0180x over previous
//
#include <hip/hip_runtime.h>
#include <math.h>

// Problem constants (from reference)
#define BB 4
#define HH 704
#define WW 704
#define MM 32
#define PP 128
#define NNEG 129
#define RR 1
#define GAIN 2.0f
#define HW (HH * WW)

// Only losses[-1] (batch b = B-1 = 3) is returned.
// Work items flattened, one per thread:
//   [0, 256)        : cls positive  (a0 = (i/128)*2, p = i%128), label 1
//   [256, 514)      : cls negative  (j = i-256; a0 = (j/129)*2, n = j%129), label 0
//   [514, 578)      : regression    (k = i-514; a = k&1, m = k>>1), 7 components
// Single block, 640 threads (10 waves) -> 2 HBM-latency rounds (idx -> gather),
// then wave shuffle + LDS block reduction.

#define NTHREADS 640
#define NWAVES (NTHREADS / 64)

__global__ __launch_bounds__(NTHREADS) void loss_total_kernel(
    const float* __restrict__ rb,      // (B, M, 7)
    const float* __restrict__ pc,      // (B, 4, H, W)
    const float* __restrict__ pr,      // (B, 14, H, W)
    const float* __restrict__ anchor,  // (2, 7, H, W)
    const int* __restrict__ pidx,      // (B, P, 2)
    const int* __restrict__ nidx,      // (B, NN, 2)
    const int* __restrict__ ridx,      // (B, M, R, 2)
    float* __restrict__ out)           // scalar
{
    const int tid = threadIdx.x;
    const int b = BB - 1;

    const float* rb_b   = rb + (size_t)b * MM * 7;
    const float* pc_b   = pc + (size_t)b * 4 * HW;
    const float* pr_b   = pr + (size_t)b * 14 * HW;
    const int2*  pidx_b = (const int2*)(pidx + (size_t)b * PP * 2);
    const int2*  nidx_b = (const int2*)(nidx + (size_t)b * NNEG * 2);
    const int2*  ridx_b = (const int2*)(ridx + (size_t)b * MM * RR * 2);

    float acc = 0.0f;

    if (tid < 514) {
        // ---- classification item ----
        int a0, scol;
        float inv_n;
        int2 yx;
        if (tid < 256) {              // positive, label = 1
            a0   = (tid >> 7) * 2;    // tid/128 in {0,1} -> channel pair
            yx   = pidx_b[tid & 127];
            scol = 1;
            inv_n = 1.0f / PP;
        } else {                      // negative, label = 0
            int j = tid - 256;
            a0   = (j / NNEG) * 2;
            yx   = nidx_b[j % NNEG];
            scol = 0;
            inv_n = 1.0f / NNEG;
        }
        size_t pix = (size_t)yx.x * WW + yx.y;
        float l0 = pc_b[(size_t)a0       * HW + pix];
        float l1 = pc_b[(size_t)(a0 + 1) * HW + pix];
        float mx  = fmaxf(l0, l1);
        float lse = mx + logf(expf(l0 - mx) + expf(l1 - mx));
        float lbl = scol ? l1 : l0;
        acc = (lse - lbl) * inv_n;
    } else if (tid < 578) {
        // ---- regression item ----
        int k = tid - 514;
        int a = k & 1;
        int m = k >> 1;
        int2 yx = ridx_b[m];          // R == 1
        size_t pix = (size_t)yx.x * WW + yx.y;

        float ab[7], pb[7], rf[7];
        #pragma unroll
        for (int c = 0; c < 7; ++c) {
            ab[c] = anchor[(size_t)(a * 7 + c) * HW + pix];
            pb[c] = pr_b  [(size_t)(a * 7 + c) * HW + pix];
            rf[c] = rb_b[m * 7 + c];
        }

        float diag = sqrtf(ab[3] * ab[3] + ab[4] * ab[4]);
        float off[7];
        off[0] = (rf[0] - ab[0]) / diag;
        off[1] = (rf[1] - ab[1]) / diag;
        off[2] = (rf[2] - ab[2]) / ab[5];
        off[3] = logf(rf[3] / ab[3]);
        off[4] = logf(rf[4] / ab[4]);
        off[5] = logf(rf[5] / ab[5]);
        float dth = rf[6] - ab[6];
        off[6] = atan2f(sinf(dth), cosf(dth));

        float s = 0.0f;
        #pragma unroll
        for (int c = 0; c < 7; ++c) {
            float d = pb[c] - off[c];
            float ad = fabsf(d);
            s += (ad < 1.0f) ? 0.5f * d * d : (ad - 0.5f);
        }
        acc = s * (GAIN / (float)(RR * 2 * 7));
    }

    // ---- reduction: shuffle within each of 10 waves, then LDS ----
    #pragma unroll
    for (int off = 32; off > 0; off >>= 1)
        acc += __shfl_down(acc, off, 64);

    __shared__ float wsum[NWAVES];
    int wave = tid >> 6;
    int lane = tid & 63;
    if (lane == 0) wsum[wave] = acc;
    __syncthreads();
    if (tid == 0) {
        float t = 0.0f;
        #pragma unroll
        for (int w = 0; w < NWAVES; ++w) t += wsum[w];
        out[0] = t;
    }
}

extern "C" void kernel_launch(void* const* d_in, const int* in_sizes, int n_in,
                              void* d_out, int out_size, void* d_ws, size_t ws_size,
                              hipStream_t stream) {
    const float* rb     = (const float*)d_in[0];
    const float* pc     = (const float*)d_in[1];
    const float* pr     = (const float*)d_in[2];
    const float* anchor = (const float*)d_in[3];
    const int*   pidx   = (const int*)d_in[4];
    const int*   nidx   = (const int*)d_in[5];
    const int*   ridx   = (const int*)d_in[6];
    float* out = (float*)d_out;

    loss_total_kernel<<<1, NTHREADS, 0, stream>>>(rb, pc, pr, anchor, pidx, nidx, ridx, out);
}